// Round 10
// baseline (271.750 us; speedup 1.0000x reference)
//
#include <hip/hip_runtime.h>
#include <math.h>

#define S_ 2048
#define E_ 2048
#define H_ 16
#define D_ 128

typedef _Float16 f16;
typedef _Float16 f16x8 __attribute__((ext_vector_type(8)));
typedef _Float16 f16x4 __attribute__((ext_vector_type(4)));
typedef float f32x4 __attribute__((ext_vector_type(4)));

// async global->LDS, 16B per lane. LDS dest must be wave-uniform base + lane*16.
#define GLDS(g, l)                                                            \
    __builtin_amdgcn_global_load_lds(                                         \
        (const __attribute__((address_space(1))) void*)(g),                   \
        (__attribute__((address_space(3))) void*)(l), 16, 0, 0)

// ---------------------------------------------------------------- convert (fused: x, w_qkv, w_out)
__global__ __launch_bounds__(256) void cvt_all(const float* __restrict__ x,
                                               const float* __restrict__ wq,
                                               const float* __restrict__ wo,
                                               f16* __restrict__ xb,
                                               f16* __restrict__ wqb,
                                               f16* __restrict__ wob) {
    const int b = blockIdx.x;
    const float* in;
    f16* out;
    int lb;
    if (b < 4096)       { in = x;  out = xb;  lb = b; }
    else if (b < 16384) { in = wq; out = wqb; lb = b - 4096; }
    else                { in = wo; out = wob; lb = b - 16384; }
    const int i = (lb * 256 + threadIdx.x) * 4;
    float4 v = *(const float4*)(in + i);
    f16x4 o;
    o[0] = (f16)v.x; o[1] = (f16)v.y; o[2] = (f16)v.z; o[3] = (f16)v.w;
    *(f16x4*)(out + i) = o;
}

// ---------------------------------------------------------------- QKV GEMM (phased, counted vmcnt)
// T3+T4 port: 2-phase hit its ceiling (R9: 805 TF, MfmaUtil 32%, conflicts 0,
// FETCH ideal -> the stall is the per-iter vmcnt(0)+barrier drain, m233).
// BM=256 x BN=192 -> grid 8x32 = 256 blocks = EXACTLY 1/CU. 8 waves (512thr),
// per-wave C = 128x48 (acc[8][3]). BK=64, 32 K-tiles, 4 phases/K-tile:
//   {ds_read A-quarter (+B held in regs from phase0) | 2 GLDS staging units
//    -> barrier -> lgkmcnt(0)+sched_barrier -> setprio(1) 12 MFMA setprio(0)
//    -> counted vmcnt -> barrier}
// vmcnt(4)@p1, vmcnt(1)@p3 (NEVER 0): staging order B0,B1|B2,Aq0|Aq2,Aq1|Aq3
// makes the in-order vmcnt guarantee exactly the units the next phases read.
// LDS 112KB (A 2x32K dbuf + B 2x24K dbuf), swizzle via pre-swizzled GLDS src
// (R8-verified conflict-free).
__global__ __launch_bounds__(512, 1) void gemm_qkv(const f16* __restrict__ A,
                                                   const f16* __restrict__ B,
                                                   const float* __restrict__ bias,
                                                   f16* __restrict__ Qm,
                                                   f16* __restrict__ Km,
                                                   f16* __restrict__ VTm) {
    __shared__ __align__(16) f16 Abuf[2][256 * 64];   // 2 x 32KB
    __shared__ __align__(16) f16 Bbuf[2][192 * 64];   // 2 x 24KB
    const int tid  = threadIdx.x;
    const int lane = tid & 63;
    const int wave = tid >> 6;
    const int lm = lane & 15, quad = lane >> 4;
    const int wm = wave >> 2, wn = wave & 3;
    const int tn0 = blockIdx.x * 192;
    const int tm0 = blockIdx.y * 256;
    const int e7 = lm & 7;

    // staging: each 64-row x 64-col unit = 512 chunks of 16B = 1 chunk/thread.
    // LDS linear (dest = unitbase + tid*16B); global src column pre-swizzled.
    const int srow = tid >> 3, sch = tid & 7;
    const int schA = (sch ^ (srow & 7)) * 8;
    const f16* Agbase = A + (size_t)(tm0 + srow) * E_ + schA;  // + q*64*E + kt*64
    const f16* Bgbase = B + (size_t)(tn0 + srow) * E_ + schA;  // + u*64*E + kt*64
    const int ldsoff = tid * 8;                                 // + unit*4096

#define STAGE_AU(SB, KS, Q) GLDS(Agbase + (size_t)(Q) * 64 * E_ + (KS), &Abuf[SB][(Q) * 4096 + ldsoff])
#define STAGE_BU(SB, KS, U) GLDS(Bgbase + (size_t)(U) * 64 * E_ + (KS), &Bbuf[SB][(U) * 4096 + ldsoff])

#define PH_READ_A(MQ)                                                          \
    _Pragma("unroll") for (int kk = 0; kk < 2; kk++)                           \
    _Pragma("unroll") for (int ii = 0; ii < 2; ii++)                           \
        af[kk][ii] = *(const f16x8*)&Abuf[b][(wm * 128 + ((MQ) * 2 + ii) * 16 + lm) * 64 + \
                                             (((kk * 4 + quad) ^ e7) * 8)];

#define PH_MFMA(MQ)                                                            \
    __builtin_amdgcn_s_barrier();                                              \
    asm volatile("s_waitcnt lgkmcnt(0)" ::: "memory");                         \
    __builtin_amdgcn_sched_barrier(0);                                         \
    __builtin_amdgcn_s_setprio(1);                                             \
    _Pragma("unroll") for (int kk = 0; kk < 2; kk++)                           \
    _Pragma("unroll") for (int ii = 0; ii < 2; ii++)                           \
    _Pragma("unroll") for (int j = 0; j < 3; j++)                              \
        acc[(MQ) * 2 + ii][j] = __builtin_amdgcn_mfma_f32_16x16x32_f16(        \
            af[kk][ii], bf[kk][j], acc[(MQ) * 2 + ii][j], 0, 0, 0);            \
    __builtin_amdgcn_s_setprio(0);

    const f32x4 vzero = {0.f, 0.f, 0.f, 0.f};
    f32x4 acc[8][3];
#pragma unroll
    for (int i = 0; i < 8; i++)
#pragma unroll
        for (int j = 0; j < 3; j++) acc[i][j] = vzero;

    // prologue: stage K-tiles 0 (buf0) and 1 (buf1); unit order per tile:
    // B0,B1,B2,Aq0,Aq2,Aq1,Aq3. Then vmcnt(8): kt0 units 1-6 landed.
#pragma unroll
    for (int kt = 0; kt < 2; ++kt) {
        const int ks = kt * 64;
        STAGE_BU(kt, ks, 0); STAGE_BU(kt, ks, 1); STAGE_BU(kt, ks, 2);
        STAGE_AU(kt, ks, 0); STAGE_AU(kt, ks, 2); STAGE_AU(kt, ks, 1); STAGE_AU(kt, ks, 3);
    }
    asm volatile("s_waitcnt vmcnt(8)" ::: "memory");
    __builtin_amdgcn_s_barrier();

    f16x8 bf[2][3];
#pragma unroll 1
    for (int kt = 0; kt < 32; ++kt) {
        const int b  = kt & 1;
        const int sb = b ^ 1;
        const bool st = (kt >= 1) && (kt < 31);
        const int ks = (kt + 1) * 64;
        f16x8 af[2][2];

        // ---- phase 0: read B (held for all 4 phases) + A quarter 0
        PH_READ_A(0)
#pragma unroll
        for (int kk = 0; kk < 2; kk++)
#pragma unroll
            for (int j = 0; j < 3; j++)
                bf[kk][j] = *(const f16x8*)&Bbuf[b][(wn * 48 + j * 16 + lm) * 64 +
                                                    (((kk * 4 + quad) ^ e7) * 8)];
        if (st) { STAGE_BU(sb, ks, 0); STAGE_BU(sb, ks, 1); }
        PH_MFMA(0)
        __builtin_amdgcn_s_barrier();

        // ---- phase 1
        PH_READ_A(1)
        if (st) { STAGE_BU(sb, ks, 2); STAGE_AU(sb, ks, 0); }
        PH_MFMA(1)
        asm volatile("s_waitcnt vmcnt(4)" ::: "memory");   // this K-tile's Aq3 landed
        __builtin_amdgcn_s_barrier();

        // ---- phase 2
        PH_READ_A(2)
        if (st) { STAGE_AU(sb, ks, 2); STAGE_AU(sb, ks, 1); }
        PH_MFMA(2)
        __builtin_amdgcn_s_barrier();

        // ---- phase 3
        PH_READ_A(3)
        if (st) { STAGE_AU(sb, ks, 3); }
        PH_MFMA(3)
        asm volatile("s_waitcnt vmcnt(1)" ::: "memory");   // next K-tile units 1-6 landed
        __builtin_amdgcn_s_barrier();
    }

    const float qscale = 0.08838834764831845f;  // 1/sqrt(128), prefolded into Q
#pragma unroll
    for (int ai = 0; ai < 8; ai++) {
#pragma unroll
        for (int j = 0; j < 3; j++) {
            const int n = tn0 + wn * 48 + j * 16 + lm;
            const int which = n >> 11;
            const int h = (n >> 7) & 15;
            const int d = n & 127;
            const float bv = bias[n];
#pragma unroll
            for (int r = 0; r < 4; r++) {
                const int m = tm0 + wm * 128 + ai * 16 + quad * 4 + r;
                float fv = acc[ai][j][r] + bv;
                if (which == 0)      Qm[((size_t)h * S_ + m) * D_ + d] = (f16)(fv * qscale);
                else if (which == 1) Km[((size_t)h * S_ + m) * D_ + d] = (f16)fv;
                else                 VTm[((size_t)h * D_ + d) * S_ + m] = (f16)fv;
            }
        }
    }
#undef STAGE_AU
#undef STAGE_BU
#undef PH_READ_A
#undef PH_MFMA
}

// ---------------------------------------------------------------- attention (partial)
// R7 structure (verified): GLDS pre-swizzled staging, K/V double-buffered with
// ONE barrier/iter, Ps 2KB/wave, defer-max, 2 q-row-tiles/wave, flash-decode
// segments of 6 kv-tiles -> 816 uniform blocks; LDS 72KB -> 2 blocks/CU.
__global__ __launch_bounds__(256, 2) void attn_part(const f16* __restrict__ Qm,
                                                    const f16* __restrict__ Km,
                                                    const f16* __restrict__ VTm,
                                                    f16* __restrict__ Om,
                                                    f16* __restrict__ Opart,
                                                    float2* __restrict__ Mlp) {
    __shared__ __align__(16) f16 Ks[2][64 * 128];   // [buf][key][d-chunk swizzled]
    __shared__ __align__(16) f16 VTs[2][128 * 64];  // [buf][d][key-chunk swizzled]
    __shared__ __align__(16) f16 Ps[4][1024];       // per-wave 2KB, reused P0/P1

    const int tid  = threadIdx.x;
    const int lane = tid & 63, wave = tid >> 6;
    const int lm = lane & 15, quad = lane >> 4;
    const int bx = blockIdx.x;
    const int h  = bx & 15;
    const int u  = 50 - (bx >> 4);   // canonical unit index, heavy-first dispatch

    // unit -> (128-row q-tile qt, kv-segment of 6 tiles). tiles(qt) = 2qt+2.
    int qt, seg;
    if (u < 3)       { qt = u;                 seg = 0; }
    else if (u < 9)  { qt = 3  + (u - 3) / 2;  seg = (u - 3) % 2; }
    else if (u < 18) { qt = 6  + (u - 9) / 3;  seg = (u - 9) % 3; }
    else if (u < 30) { qt = 9  + (u - 18) / 4; seg = (u - 18) % 4; }
    else if (u < 45) { qt = 12 + (u - 30) / 5; seg = (u - 30) % 5; }
    else             { qt = 15;                seg = u - 45; }
    const int t0 = seg * 6;
    const int ntiles = 2 * qt + 2;
    const int t1 = (t0 + 6 < ntiles) ? (t0 + 6) : ntiles;

    const f16* KmH  = Km  + (size_t)h * S_ * D_;
    const f16* VTmH = VTm + (size_t)h * D_ * S_;
    const f16* QmH  = Qm  + (size_t)h * S_ * D_;

    // GLDS staging offsets: linear LDS slot c -> inverse-swizzled global chunk.
    int kgo[4], vgo[4];
#pragma unroll
    for (int i = 0; i < 4; i++) {
        int c = (wave * 4 + i) * 64 + lane;          // 16B-chunk linear index
        int key = c >> 4, dcS = c & 15;
        int dc = (dcS & 8) | ((dcS & 7) ^ (key & 7));
        kgo[i] = key * 128 + dc * 8;
        int d = c >> 3, scS = c & 7;
        int sc = scS ^ (d & 7);
        vgo[i] = d * 2048 + sc * 8;
    }

#define STAGE(B, T)                                                           \
    {                                                                         \
        const f16* kt_ = KmH + (size_t)(T) * 8192;                            \
        const f16* vt_ = VTmH + (T) * 64;                                     \
        _Pragma("unroll")                                                     \
        for (int i = 0; i < 4; i++) {                                         \
            GLDS(kt_ + kgo[i], &Ks[B][(wave * 4 + i) * 512]);                 \
            GLDS(vt_ + vgo[i], &VTs[B][(wave * 4 + i) * 512]);                \
        }                                                                     \
    }

    const f32x4 vzero = {0.f, 0.f, 0.f, 0.f};
    f32x4 o0[8], o1[8];
#pragma unroll
    for (int f = 0; f < 8; f++) { o0[f] = vzero; o1[f] = vzero; }
    float mi0 = -INFINITY, li0 = 0.f;
    float mi1 = -INFINITY, li1 = 0.f;

    const int q0c = qt * 128 + wave * 32;          // wave's 32-row chunk
    const int qr0 = q0c + lm;                      // n=0 row
    const int qr1 = q0c + 16 + lm;                 // n=1 row
    f16x8 qf0[4], qf1[4];
#pragma unroll
    for (int kc = 0; kc < 4; kc++) {
        qf0[kc] = *(const f16x8*)(QmH + (size_t)qr0 * D_ + kc * 32 + quad * 8);
        qf1[kc] = *(const f16x8*)(QmH + (size_t)qr1 * D_ + kc * 32 + quad * 8);
    }

    char* psb = (char*)&Ps[wave][0];
    const int swz = (lm & 7) << 4;

    // prologue: stage first tile into buffer 0
    STAGE(0, t0);
    __syncthreads();

    for (int t = t0; t < t1; t++) {
        const int cur = (t - t0) & 1;
        const int k0 = t * 64;

        if (t + 1 < t1) STAGE(cur ^ 1, t + 1);   // async into other buffer

        // ---- S^T = K * Q^T : each kf read feeds BOTH n-tiles
        f32x4 sfr0[4], sfr1[4];
        __builtin_amdgcn_s_setprio(1);
#pragma unroll
        for (int j = 0; j < 4; j++) {
            f32x4 a0 = vzero, a1 = vzero;
#pragma unroll
            for (int kc = 0; kc < 4; kc++) {
                int dc = kc * 4 + quad;
                int sc = (dc & 8) | ((dc & 7) ^ (lm & 7));
                f16x8 kf = *(const f16x8*)&Ks[cur][(j * 16 + lm) * 128 + sc * 8];
                a0 = __builtin_amdgcn_mfma_f32_16x16x32_f16(kf, qf0[kc], a0, 0, 0, 0);
                a1 = __builtin_amdgcn_mfma_f32_16x16x32_f16(kf, qf1[kc], a1, 0, 0, 0);
            }
            sfr0[j] = a0; sfr1[j] = a1;
        }
        __builtin_amdgcn_s_setprio(0);

        // ---- online softmax, two independent 16-row chains (n=0, n=1)
        const bool mayMask = (k0 + 63 > q0c);
        float vmax0 = -3e38f, vmax1 = -3e38f;
#pragma unroll
        for (int j = 0; j < 4; j++)
#pragma unroll
            for (int r = 0; r < 4; r++) {
                float x0 = sfr0[j][r], x1 = sfr1[j][r];
                if (mayMask) {
                    int key = k0 + j * 16 + quad * 4 + r;
                    if (key > qr0) x0 = -1e30f;
                    if (key > qr1) x1 = -1e30f;
                }
                sfr0[j][r] = x0; sfr1[j][r] = x1;
                vmax0 = fmaxf(vmax0, x0);
                vmax1 = fmaxf(vmax1, x1);
            }
        vmax0 = fmaxf(vmax0, __shfl_xor(vmax0, 16));
        vmax0 = fmaxf(vmax0, __shfl_xor(vmax0, 32));
        vmax1 = fmaxf(vmax1, __shfl_xor(vmax1, 16));
        vmax1 = fmaxf(vmax1, __shfl_xor(vmax1, 32));
        // defer-max (T13): rescale only when a row's max grew by > 8
        if (!__all(fmaxf(vmax0 - mi0, vmax1 - mi1) <= 8.0f)) {
            const float mn0 = fmaxf(mi0, vmax0);
            const float mn1 = fmaxf(mi1, vmax1);
            const float al0 = __expf(mi0 - mn0);
            const float al1 = __expf(mi1 - mn1);
            li0 *= al0; li1 *= al1;
#pragma unroll
            for (int f = 0; f < 8; f++) {
                o0[f][0] *= al0; o0[f][1] *= al0; o0[f][2] *= al0; o0[f][3] *= al0;
                o1[f][0] *= al1; o1[f][1] *= al1; o1[f][2] *= al1; o1[f][3] *= al1;
            }
            mi0 = mn0; mi1 = mn1;
        }
        // P (bounded by e^8, f16-safe): n=0 through the 2KB Ps, then n=1
        float rs0 = 0.f, rs1 = 0.f;
#pragma unroll
        for (int j = 0; j < 4; j++) {
            f16x4 pk0;
#pragma unroll
            for (int r = 0; r < 4; r++) {
                float p0 = __expf(sfr0[j][r] - mi0);
                rs0 += p0;
                pk0[r] = (f16)p0;
            }
            *(f16x4*)(psb + lm * 128 + ((j * 32 + quad * 8) ^ swz)) = pk0;
        }
        f16x8 pb0[2];
#pragma unroll
        for (int kc = 0; kc < 2; kc++)
            pb0[kc] = *(const f16x8*)(psb + lm * 128 + ((kc * 64 + quad * 16) ^ swz));
#pragma unroll
        for (int j = 0; j < 4; j++) {
            f16x4 pk1;
#pragma unroll
            for (int r = 0; r < 4; r++) {
                float p1 = __expf(sfr1[j][r] - mi1);
                rs1 += p1;
                pk1[r] = (f16)p1;
            }
            *(f16x4*)(psb + lm * 128 + ((j * 32 + quad * 8) ^ swz)) = pk1;
        }
        f16x8 pb1[2];
#pragma unroll
        for (int kc = 0; kc < 2; kc++)
            pb1[kc] = *(const f16x8*)(psb + lm * 128 + ((kc * 64 + quad * 16) ^ swz));
        rs0 += __shfl_xor(rs0, 16);
        rs0 += __shfl_xor(rs0, 32);
        rs1 += __shfl_xor(rs1, 16);
        rs1 += __shfl_xor(rs1, 32);
        li0 += rs0;
        li1 += rs1;

        // ---- O^T += V^T * P^T : each vf read feeds BOTH n-tiles
        __builtin_amdgcn_s_setprio(1);
#pragma unroll
        for (int f = 0; f < 8; f++) {
#pragma unroll
            for (int kc = 0; kc < 2; kc++) {
                int sc = (kc * 4 + quad) ^ (lm & 7);
                f16x8 vf = *(const f16x8*)&VTs[cur][(f * 16 + lm) * 64 + sc * 8];
                o0[f] = __builtin_amdgcn_mfma_f32_16x16x32_f16(vf, pb0[kc], o0[f], 0, 0, 0);
                o1[f] = __builtin_amdgcn_mfma_f32_16x16x32_f16(vf, pb1[kc], o1[f], 0, 0, 0);
            }
        }
        __builtin_amdgcn_s_setprio(0);

        __syncthreads();   // own GLDS drained (hidden by compute); all waves done
    }

    const float inv0 = 1.f / li0;
    const float inv1 = 1.f / li1;
    if (qt < 3) {
        // single segment: normalized output directly
#pragma unroll
        for (int f = 0; f < 8; f++) {
            f16x4 ov0, ov1;
#pragma unroll
            for (int r = 0; r < 4; r++) {
                ov0[r] = (f16)(o0[f][r] * inv0);
                ov1[r] = (f16)(o1[f][r] * inv1);
            }
            *(f16x4*)(Om + (size_t)qr0 * E_ + h * 128 + f * 16 + quad * 4) = ov0;
            *(f16x4*)(Om + (size_t)qr1 * E_ + h * 128 + f * 16 + quad * 4) = ov1;
        }
    } else {
        // partial: NORMALIZED O (f16) + per-row (m, l)
        const int unit = h * 51 + u;
        f16* op0 = Opart + (size_t)unit * 16384 + (wave * 32 + lm) * 128;
        f16* op1 = op0 + 16 * 128;
#pragma unroll
        for (int f = 0; f < 8; f++) {
            f16x4 ov0, ov1;
#pragma unroll
            for (int r = 0; r < 4; r++) {
                ov0[r] = (f16)(o0[f][r] * inv0);
                ov1[r] = (f16)(o1[f][r] * inv1);
            }
            *(f16x4*)(op0 + f * 16 + quad * 4) = ov0;
            *(f16x4*)(op1 + f * 16 + quad * 4) = ov1;
        }
        if (quad == 0) {
            Mlp[unit * 128 + wave * 32 + lm]      = make_float2(mi0, li0);
            Mlp[unit * 128 + wave * 32 + 16 + lm] = make_float2(mi1, li1);
        }
    }
#undef STAGE
}

// ---------------------------------------------------------------- attention merge
__global__ __launch_bounds__(256) void attn_merge(const f16* __restrict__ Opart,
                                                  const float2* __restrict__ Mlp,
                                                  f16* __restrict__ Om) {
    const int idx = blockIdx.x * 256 + threadIdx.x;   // 851968 total
    const int d4  = idx & 31;
    const int h   = (idx >> 5) & 15;
    const int r5  = idx >> 9;            // 0..1663
    const int row = 384 + r5;
    const int qt  = row >> 7;            // 3..15 (128-row tiles)
    const int rw  = row & 127;
    int ub, nseg;
    if (qt < 6)       { ub = 3  + (qt - 3) * 2;  nseg = 2; }
    else if (qt < 9)  { ub = 9  + (qt - 6) * 3;  nseg = 3; }
    else if (qt < 12) { ub = 18 + (qt - 9) * 4;  nseg = 4; }
    else if (qt < 15) { ub = 30 + (qt - 12) * 5; nseg = 5; }
    else              { ub = 45;                 nseg = 6; }
    const int base_unit = h * 51 + ub;

    float m = -INFINITY;
    for (int s = 0; s < nseg; s++)
        m = fmaxf(m, Mlp[(base_unit + s) * 128 + rw].x);

    float L = 0.f;
    float a0 = 0.f, a1 = 0.f, a2 = 0.f, a3 = 0.f;
    for (int s = 0; s < nseg; s++) {
        float2 ml = Mlp[(base_unit + s) * 128 + rw];
        float wl = __expf(ml.x - m) * ml.y;
        L += wl;
        f16x4 ov = *(const f16x4*)(Opart + (size_t)(base_unit + s) * 16384 + rw * 128 + d4 * 4);
        a0 += wl * (float)ov[0];
        a1 += wl * (float)ov[1];
        a2 += wl * (float)ov[2];
        a3 += wl * (float)ov[3];
    }
    const float inv = 1.f / L;
    f16x4 res;
    res[0] = (f16)(a0 * inv); res[1] = (f16)(a1 * inv);
    res[2] = (f16)(a2 * inv); res[3] = (f16)(a3 * inv);
    *(f16x4*)(Om + (size_t)row * E_ + h * 128 + d4 * 4) = res;
}

// ---------------------------------------------------------------- out GEMM
// BK=64, conflict-free swizzle (R8-verified). Plain 2D grid: 16 = 0 mod 8 ->
// bx = bid mod 8 per XCD -> 2 B-panels/XCD (1MB, L2-resident), A streams.
__global__ __launch_bounds__(256) void gemm_out(const f16* __restrict__ A,
                                                const f16* __restrict__ B,
                                                const float* __restrict__ bias,
                                                float* __restrict__ Cout) {
    __shared__ __align__(16) f16 As[64 * 64];    // 8KB
    __shared__ __align__(16) f16 Bs[128 * 64];   // 16KB
    const int tid  = threadIdx.x;
    const int lane = tid & 63, wave = tid >> 6;
    const int lm = lane & 15, quad = lane >> 4;
    const int wm = wave >> 1, wn = wave & 1;
    const int tn0 = blockIdx.x * 128;
    const int tm0 = blockIdx.y * 64;

    const f16* Aga[2];
    const f16* Bga[4];
    f16* Ald[2];
    f16* Bld[4];
#pragma unroll
    for (int i = 0; i < 2; i++) {
        int c = i * 256 + tid;
        int row = c >> 3, ch = c & 7;
        int srcoff = row * E_ + ((ch ^ (row & 7)) * 8);
        Aga[i] = A + (size_t)tm0 * E_ + srcoff;
        Ald[i] = &As[c * 8];
    }
#pragma unroll
    for (int i = 0; i < 4; i++) {
        int c = i * 256 + tid;
        int row = c >> 3, ch = c & 7;
        int srcoff = row * E_ + ((ch ^ (row & 7)) * 8);
        Bga[i] = B + (size_t)tn0 * E_ + srcoff;
        Bld[i] = &Bs[c * 8];
    }

    const f32x4 vzero = {0.f, 0.f, 0.f, 0.f};
    f32x4 acc[2][4];
#pragma unroll
    for (int i = 0; i < 2; i++)
#pragma unroll
        for (int j = 0; j < 4; j++) acc[i][j] = vzero;

    const int e7 = lm & 7;
    for (int k0 = 0; k0 < E_; k0 += 64) {
        __syncthreads();
#pragma unroll
        for (int i = 0; i < 2; i++) GLDS(Aga[i] + k0, Ald[i]);
#pragma unroll
        for (int i = 0; i < 4; i++) GLDS(Bga[i] + k0, Bld[i]);
        __syncthreads();
#pragma unroll
        for (int kk = 0; kk < 2; kk++) {
            f16x8 af[2], bfr[4];
#pragma unroll
            for (int i = 0; i < 2; i++)
                af[i] = *(const f16x8*)&As[(wm * 32 + i * 16 + lm) * 64 +
                                           (((kk * 4 + quad) ^ e7) * 8)];
#pragma unroll
            for (int j = 0; j < 4; j++)
                bfr[j] = *(const f16x8*)&Bs[(wn * 64 + j * 16 + lm) * 64 +
                                            (((kk * 4 + quad) ^ e7) * 8)];
#pragma unroll
            for (int i = 0; i < 2; i++)
#pragma unroll
                for (int j = 0; j < 4; j++)
                    acc[i][j] = __builtin_amdgcn_mfma_f32_16x16x32_f16(af[i], bfr[j],
                                                                       acc[i][j], 0, 0, 0);
        }
    }

#pragma unroll
    for (int i = 0; i < 2; i++) {
#pragma unroll
        for (int j = 0; j < 4; j++) {
            const int n = tn0 + wn * 64 + j * 16 + lm;
            const float bv = bias[n];
#pragma unroll
            for (int r = 0; r < 4; r++) {
                const int m = tm0 + wm * 32 + i * 16 + quad * 4 + r;
                Cout[(size_t)m * E_ + n] = acc[i][j][r] + bv;
            }
        }
    }
}

// ---------------------------------------------------------------- launch
extern "C" void kernel_launch(void* const* d_in, const int* in_sizes, int n_in,
                              void* d_out, int out_size, void* d_ws, size_t ws_size,
                              hipStream_t stream) {
    const float* x     = (const float*)d_in[0];
    const float* w_qkv = (const float*)d_in[1];
    const float* b_qkv = (const float*)d_in[2];
    const float* w_out = (const float*)d_in[3];
    const float* b_out = (const float*)d_in[4];
    float* out = (float*)d_out;

    char* ws = (char*)d_ws;
    f16* xb  = (f16*)ws; ws += (size_t)S_ * E_ * 2;
    f16* wqb = (f16*)ws; ws += (size_t)3 * E_ * E_ * 2;
    f16* wob = (f16*)ws; ws += (size_t)E_ * E_ * 2;
    f16* Qm  = (f16*)ws; ws += (size_t)H_ * S_ * D_ * 2;
    f16* Km  = (f16*)ws; ws += (size_t)H_ * S_ * D_ * 2;
    f16* VTm = (f16*)ws; ws += (size_t)H_ * D_ * S_ * 2;
    f16* Om  = (f16*)ws; ws += (size_t)S_ * E_ * 2;

    // attn partials reuse the xb+wqb region (32MB, dead after gemm_qkv):
    // Opart 816 units x 128 rows x 128 d (f16) = 25.5MB; Mlp at +27MB.
    f16*    Opart = (f16*)d_ws;
    float2* Mlp   = (float2*)((char*)d_ws + (27u << 20));

    cvt_all<<<20480, 256, 0, stream>>>(x, w_qkv, w_out, xb, wqb, wob);
    gemm_qkv<<<dim3(32, 8), 512, 0, stream>>>(xb, wqb, b_qkv, Qm, Km, VTm);
    attn_part<<<816, 256, 0, stream>>>(Qm, Km, VTm, Om, Opart, Mlp);
    attn_merge<<<3328, 256, 0, stream>>>(Opart, Mlp, Om);
    gemm_out<<<dim3(16, 32), 256, 0, stream>>>(Om, wob, b_out, out);
}